// Round 7
// baseline (2446.175 us; speedup 1.0000x reference)
//
#include <hip/hip_runtime.h>
#include <hip/hip_bf16.h>

#define TT 4096
#define FF 80
#define HH 64
#define NB 128
#define TB 256    // proj: timesteps per block
#define CT 8      // proj: timesteps per staging phase
#define XPAD 104  // proj LDS row stride in bf16 elems

using short8  = __attribute__((ext_vector_type(8))) short;   // 8 bf16 = 4 VGPR
using floatx4 = __attribute__((ext_vector_type(4))) float;

__device__ __forceinline__ float sigm(float x)  { return __builtin_amdgcn_rcpf(1.0f + __expf(-x)); }
__device__ __forceinline__ float tanh_f(float x){ return 1.0f - 2.0f * __builtin_amdgcn_rcpf(1.0f + __expf(2.0f * x)); }

__device__ __forceinline__ unsigned short f2bf(float f) {    // RNE f32->bf16
    unsigned u = __builtin_bit_cast(unsigned, f);
    u += 0x7fffu + ((u >> 16) & 1u);
    return (unsigned short)(u >> 16);
}
__device__ __forceinline__ float bf2f(unsigned short u) {
    return __builtin_bit_cast(float, (unsigned)u << 16);
}
__device__ __forceinline__ unsigned packbf2(float a, float b) {
    return (unsigned)f2bf(a) | ((unsigned)f2bf(b) << 16);
}

// LDS-visibility-only barrier: global loads stay in flight across it.
__device__ __forceinline__ void bar_lgkm() {
    asm volatile("s_waitcnt lgkmcnt(0)" ::: "memory");
    __builtin_amdgcn_s_barrier();
}

__device__ __forceinline__ floatx4 mfma16(short8 a, short8 b, floatx4 c) {
    return __builtin_amdgcn_mfma_f32_16x16x32_bf16(a, b, c, 0, 0, 0);
}

// quad broadcast via DPP (register-only, no LDS)
template <int CTRL>
__device__ __forceinline__ float qb(float v) {
    return __builtin_bit_cast(float,
        __builtin_amdgcn_mov_dpp(__builtin_bit_cast(int, v), CTRL, 0xF, 0xF, false));
}

// pin a float4's components into VGPRs: asm-defined values cannot be
// re-materialized by reloading from memory (the round-1..5 failure mode).
// NOTE: macro param must NOT be named 'w' ('w.w' would expand both tokens).
#define PIN4(vv) asm volatile("" : "+v"((vv).x), "+v"((vv).y), "+v"((vv).z), "+v"((vv).w))

#define MAC(W,H) a0 = fmaf((W).x,(H).x,a0); a1 = fmaf((W).y,(H).y,a1); \
                 a2 = fmaf((W).z,(H).z,a2); a3 = fmaf((W).w,(H).w,a3);

// ---------------------------------------------------------------------------
// PROJ (MFMA): PRE[chain = dir*128+b][t][perm(k)] (bf16) =
//   b_ih[k]+b_hh[k] + sum_f w_ih[k][f]*x[b][te][f],  te = t (fwd) / TT-1-t (bwd)
// perm(k) = (k&63)*4 + (k>>6) so the scan's thread tid = u*4+q reads PRE at
// lane-linear position tid. MFMA tiling: A = x rows (16 batches), B = w_ih^T,
// K = 80 zero-padded to 96; B-fragments register-resident.
// ---------------------------------------------------------------------------
__global__ __launch_bounds__(256, 1)
void lstm_proj_mfma(const float* __restrict__ x,
                    const float* __restrict__ w_ih_f, const float* __restrict__ b_ih_f,
                    const float* __restrict__ b_hh_f,
                    const float* __restrict__ w_ih_b, const float* __restrict__ b_ih_b,
                    const float* __restrict__ b_hh_b,
                    unsigned short* __restrict__ pre)
{
    const int blk   = blockIdx.x;        // 256 = 16 dgrp x 16 ttile
    const int ttile = blk & 15;
    const int dgrp  = blk >> 4;
    const int dir   = dgrp >> 3;
    const int bgrp  = dgrp & 7;
    const int tid   = threadIdx.x;
    const int wv    = tid >> 6;
    const int l     = tid & 63;
    const int b16   = l & 15;            // A row (batch) / C col (n within tile)
    const int g     = l >> 4;            // k-group / C row group
    const int t0    = ttile * TB;

    const float* __restrict__ wih = dir ? w_ih_b : w_ih_f;
    const float* __restrict__ bi  = dir ? b_ih_b : b_ih_f;
    const float* __restrict__ bh  = dir ? b_hh_b : b_hh_f;

    // B-fragments: wave wv owns tiles tau = 4*wv + tp. col n = 16*tau + b16,
    // k = 32*kap + 8*g + j (zero for k >= 80).
    short8 Bf[4][3];
    float  bias[4];
    #pragma unroll
    for (int tp = 0; tp < 4; ++tp) {
        const int n = 64 * wv + 16 * tp + b16;
        bias[tp] = bi[n] + bh[n];
        #pragma unroll
        for (int kap = 0; kap < 3; ++kap) {
            const int f0 = 32 * kap + 8 * g;
            float f[8];
            if (f0 < FF) {
                const float4 v0 = *reinterpret_cast<const float4*>(wih + n * FF + f0);
                const float4 v1 = *reinterpret_cast<const float4*>(wih + n * FF + f0 + 4);
                f[0]=v0.x; f[1]=v0.y; f[2]=v0.z; f[3]=v0.w;
                f[4]=v1.x; f[5]=v1.y; f[6]=v1.z; f[7]=v1.w;
            } else {
                #pragma unroll
                for (int j = 0; j < 8; ++j) f[j] = 0.0f;
            }
            short8 s;
            #pragma unroll
            for (int j = 0; j < 8; ++j) s[j] = (short)f2bf(f[j]);
            Bf[tp][kap] = s;
        }
    }

    // x staging LDS: [buf][CT t][16 b][XPAD] bf16; cols 80..103 stay zero.
    __shared__ __align__(16) unsigned short xa[2][CT][16][XPAD];
    for (int i = tid; i < 2 * CT * 16 * XPAD / 2; i += 256)
        reinterpret_cast<unsigned*>(&xa[0][0][0][0])[i] = 0u;
    __syncthreads();

    const int nph = TB / CT;   // 32

    {   // prologue: stage phase 0 into xa[0]
        const int t0p = t0;
        const int te_base = dir ? (TT - CT - t0p) : t0p;
        float2 st[20];
        #pragma unroll
        for (int q = 0; q < 20; ++q) {
            const int i = q * 256 + tid;
            const int b = i / 320, r2 = i % 320;
            const int te_rel = r2 / 40, fq = r2 % 40;
            st[q] = *reinterpret_cast<const float2*>(
                x + ((size_t)(bgrp * 16 + b) * TT + te_base + te_rel) * FF + 2 * fq);
        }
        #pragma unroll
        for (int q = 0; q < 20; ++q) {
            const int i = q * 256 + tid;
            const int b = i / 320, r2 = i % 320;
            const int te_rel = r2 / 40, fq = r2 % 40;
            const int t_off = dir ? (CT - 1 - te_rel) : te_rel;
            *reinterpret_cast<unsigned*>(&xa[0][t_off][b][2 * fq]) = packbf2(st[q].x, st[q].y);
        }
    }
    __syncthreads();

    #pragma unroll 1
    for (int ph = 0; ph < nph; ++ph) {
        const int cur = ph & 1;
        const bool have = (ph + 1) < nph;

        // 1) issue next-phase global loads early (hide under MFMA phase)
        float2 st[20];
        if (have) {
            const int t0p = t0 + (ph + 1) * CT;
            const int te_base = dir ? (TT - CT - t0p) : t0p;
            #pragma unroll
            for (int q = 0; q < 20; ++q) {
                const int i = q * 256 + tid;
                const int b = i / 320, r2 = i % 320;
                const int te_rel = r2 / 40, fq = r2 % 40;
                st[q] = *reinterpret_cast<const float2*>(
                    x + ((size_t)(bgrp * 16 + b) * TT + te_base + te_rel) * FF + 2 * fq);
            }
        }

        // 2) compute CT timesteps from xa[cur]
        #pragma unroll
        for (int t_off = 0; t_off < CT; ++t_off) {
            short8 A[3];
            #pragma unroll
            for (int kap = 0; kap < 3; ++kap)
                A[kap] = *reinterpret_cast<const short8*>(&xa[cur][t_off][b16][32 * kap + 8 * g]);
            const int t = t0 + ph * CT + t_off;
            #pragma unroll
            for (int tp = 0; tp < 4; ++tp) {
                floatx4 acc = {bias[tp], bias[tp], bias[tp], bias[tp]};
                acc = mfma16(A[0], Bf[tp][0], acc);
                acc = mfma16(A[1], Bf[tp][1], acc);
                acc = mfma16(A[2], Bf[tp][2], acc);
                // n = 64*wv + 16*tp + b16 ; perm(n) = (n&63)*4 + (n>>6)
                const int p = (16 * tp + b16) * 4 + wv;
                #pragma unroll
                for (int r = 0; r < 4; ++r) {
                    const int bb = dir * NB + bgrp * 16 + 4 * g + r;
                    pre[((size_t)bb * TT + t) * 256 + p] = f2bf(acc[r]);
                }
            }
        }

        // 3) write staged data to the other buffer
        if (have) {
            #pragma unroll
            for (int q = 0; q < 20; ++q) {
                const int i = q * 256 + tid;
                const int b = i / 320, r2 = i % 320;
                const int te_rel = r2 / 40, fq = r2 % 40;
                const int t_off = dir ? (CT - 1 - te_rel) : te_rel;
                *reinterpret_cast<unsigned*>(&xa[cur ^ 1][t_off][b][2 * fq]) = packbf2(st[q].x, st[q].y);
            }
        }
        bar_lgkm();   // LDS only — PRE stores keep flying
    }
}

// ---------------------------------------------------------------------------
// SCAN (quad layout): 256 blocks = 1 chain/CU. Thread = (unit u = tid>>2,
// gate q = tid&3), gate row k = q*64+u; 64 W_hh weights PINNED in VGPRs via
// asm (cannot be re-materialized -> no per-step L2 refetch). Each lane
// activates its own gate (2 trans), then 4 DPP quad-broadcasts deliver
// i,f,g,o in-register (no gate LDS, no bank conflicts). h round-trips via a
// double-buffered 64-float hbuf; one lgkm-only barrier/step; PRE ring
// (distance 4) stays in flight across the barrier.
// ---------------------------------------------------------------------------
__global__ __launch_bounds__(256, 1)
void lstm_scan_quad(const unsigned short* __restrict__ pre,  // [256][TT][256] permuted
                    const float* __restrict__ w_hh_f, const float* __restrict__ w_hh_b,
                    float* __restrict__ h_out)               // [256][64]
{
    const int chain = blockIdx.x;       // dir*128 + bat
    const int dir   = chain >> 7;
    const int tid   = threadIdx.x;
    const int u     = tid >> 2;         // hidden unit 0..63
    const int q     = tid & 3;          // 0:i 1:f 2:g 3:o
    const int k     = q * 64 + u;       // gate row in W_hh

    const float4* wr = reinterpret_cast<const float4*>(
        (dir ? w_hh_b : w_hh_f) + k * HH);
    float4 w0 = wr[0],  w1 = wr[1],  w2 = wr[2],  w3 = wr[3];
    float4 w4 = wr[4],  w5 = wr[5],  w6 = wr[6],  w7 = wr[7];
    float4 w8 = wr[8],  w9 = wr[9],  wA = wr[10], wB = wr[11];
    float4 wC = wr[12], wD = wr[13], wE = wr[14], wF = wr[15];
    PIN4(w0); PIN4(w1); PIN4(w2); PIN4(w3);
    PIN4(w4); PIN4(w5); PIN4(w6); PIN4(w7);
    PIN4(w8); PIN4(w9); PIN4(wA); PIN4(wB);
    PIN4(wC); PIN4(wD); PIN4(wE); PIN4(wF);

    // branchless activation constants: g-gate (q==2) -> tanh, else sigmoid.
    //   t = exp(es*x); r = rcp(1+t); a = cA*r + cB
    const float es = (q == 2) ?  2.0f : -1.0f;
    const float cA = (q == 2) ? -2.0f :  1.0f;
    const float cB = (q == 2) ?  1.0f :  0.0f;

    __shared__ __align__(16) float hbuf[2][HH];   // double-buffered h
    if (tid < 2 * HH) (&hbuf[0][0])[tid] = 0.0f;

    const unsigned short* __restrict__ prow =
        pre + (size_t)chain * TT * 256 + tid;
    unsigned short prr[4];               // distance-4 prefetch ring
    #pragma unroll
    for (int d = 0; d < 4; ++d) prr[d] = prow[d * 256];

    float c = 0.0f, h = 0.0f;
    __syncthreads();

    #pragma unroll 1
    for (int t = 0; t < TT; t += 4) {
        #pragma unroll
        for (int d = 0; d < 4; ++d) {
            const int cur = d & 1;       // (t+d)&1

            const float4* hb = reinterpret_cast<const float4*>(hbuf[cur]);
            float a0 = bf2f(prr[d]), a1 = 0.f, a2 = 0.f, a3 = 0.f;
            MAC(w0, hb[0]);  MAC(w1, hb[1]);  MAC(w2, hb[2]);  MAC(w3, hb[3]);
            MAC(w4, hb[4]);  MAC(w5, hb[5]);  MAC(w6, hb[6]);  MAC(w7, hb[7]);
            MAC(w8, hb[8]);  MAC(w9, hb[9]);  MAC(wA, hb[10]); MAC(wB, hb[11]);
            MAC(wC, hb[12]); MAC(wD, hb[13]); MAC(wE, hb[14]); MAC(wF, hb[15]);

            // reload ring slot for t+d+4; stays in flight across the barrier
            prr[d] = prow[(size_t)((t + d + 4) & (TT - 1)) * 256];

            const float gate = (a0 + a1) + (a2 + a3);
            // own-gate activation (2 trans)
            const float ex = __expf(es * gate);
            const float r  = __builtin_amdgcn_rcpf(1.0f + ex);
            const float a  = fmaf(cA, r, cB);

            // quad broadcast: gather i,f,g,o (register-only DPP)
            const float gi = qb<0x00>(a);
            const float gf = qb<0x55>(a);
            const float gg = qb<0xAA>(a);
            const float go = qb<0xFF>(a);

            c = fmaf(gf, c, gi * gg);
            const float e2 = __expf(2.0f * c);
            const float r2 = __builtin_amdgcn_rcpf(1.0f + e2);
            h = go * fmaf(-2.0f, r2, 1.0f);

            if (q == 0) hbuf[cur ^ 1][u] = h;   // single writer per unit
            bar_lgkm();                          // LDS visibility only
        }
    }

    if (q == 0) h_out[(size_t)chain * HH + u] = h;
}

// ---------------------------------------------------------------------------
// Fallback: fully fused scan (round-1 kernel) if ws is too small for PRE.
// ---------------------------------------------------------------------------
__global__ __launch_bounds__(256, 1)
void lstm_scan_fused_kernel(const float* __restrict__ x,
                            const float* __restrict__ w_ih_f, const float* __restrict__ w_hh_f,
                            const float* __restrict__ b_ih_f, const float* __restrict__ b_hh_f,
                            const float* __restrict__ w_ih_b, const float* __restrict__ w_hh_b,
                            const float* __restrict__ b_ih_b, const float* __restrict__ b_hh_b,
                            float* __restrict__ h_out)
{
    const int blk = blockIdx.x;
    const int dir = blk >> 7;
    const int bat = blk & 127;
    const int tid = threadIdx.x;
    const int wv  = tid >> 6;
    const int ln  = tid & 63;

    const float* __restrict__ w_ih = dir ? w_ih_b : w_ih_f;
    const float* __restrict__ w_hh = dir ? w_hh_b : w_hh_f;
    const float* __restrict__ b_ih = dir ? b_ih_b : b_ih_f;
    const float* __restrict__ b_hh = dir ? b_hh_b : b_hh_f;

    float wi[FF], wh[HH];
    #pragma unroll
    for (int f = 0; f < FF; ++f) wi[f] = w_ih[tid * FF + f];
    #pragma unroll
    for (int j = 0; j < HH; ++j) wh[j] = w_hh[tid * HH + j];
    const float bias = b_ih[tid] + b_hh[tid];

    __shared__ float xs[2][FF];
    __shared__ float hbuf[4][HH];
    __shared__ float gbuf[2][256];

    const float* __restrict__ xrow = x + (size_t)bat * (TT * FF);
    float c = 0.0f, hreg = 0.0f;
    hbuf[wv][ln] = 0.0f;

    float xA = 0.0f;
    if (tid < FF) {
        xs[0][tid] = xrow[(size_t)(dir ? (TT - 1) : 0) * FF + tid];
        xA         = xrow[(size_t)(dir ? (TT - 2) : 1) * FF + tid];
    }
    __syncthreads();

    #pragma unroll 1
    for (int t = 0; t < TT; ++t) {
        const int cur = t & 1, nxt = cur ^ 1;
        float a0 = 0.f, a1 = 0.f, a2 = 0.f, a3 = 0.f;
        const float4* xs4 = reinterpret_cast<const float4*>(xs[cur]);
        #pragma unroll
        for (int f = 0; f < FF / 4; ++f) {
            float4 v = xs4[f];
            a0 = fmaf(wi[4*f+0], v.x, a0);
            a1 = fmaf(wi[4*f+1], v.y, a1);
            a2 = fmaf(wi[4*f+2], v.z, a2);
            a3 = fmaf(wi[4*f+3], v.w, a3);
        }
        const float4* hb4 = reinterpret_cast<const float4*>(hbuf[wv]);
        #pragma unroll
        for (int j = 0; j < HH / 4; ++j) {
            float4 v = hb4[j];
            a0 = fmaf(wh[4*j+0], v.x, a0);
            a1 = fmaf(wh[4*j+1], v.y, a1);
            a2 = fmaf(wh[4*j+2], v.z, a2);
            a3 = fmaf(wh[4*j+3], v.w, a3);
        }
        gbuf[cur][tid] = ((a0 + a1) + (a2 + a3)) + bias;

        if (tid < FF) {
            if (t + 1 < TT) xs[nxt][tid] = xA;
            if (t + 2 < TT) xA = xrow[(size_t)(dir ? (TT - 3 - t) : (t + 2)) * FF + tid];
        }
        __syncthreads();

        const float gi = gbuf[cur][ln];
        const float gf = gbuf[cur][64 + ln];
        const float gg = gbuf[cur][128 + ln];
        const float go = gbuf[cur][192 + ln];
        c    = sigm(gf) * c + sigm(gi) * tanh_f(gg);
        hreg = sigm(go) * tanh_f(c);
        hbuf[wv][ln] = hreg;
    }

    if (tid < HH) h_out[(size_t)(dir * 128 + bat) * HH + tid] = hreg;
}

__global__ __launch_bounds__(64, 1)
void fc_kernel(const float* __restrict__ h_out,   // [2][NB][HH]
               const float* __restrict__ w_fc,    // [8][128]
               const float* __restrict__ b_fc,    // [8]
               float* __restrict__ out)           // [NB][8]
{
    const int b = blockIdx.x;
    const int o = threadIdx.x;
    if (o < 8) {
        float acc = b_fc[o];
        #pragma unroll 4
        for (int j = 0; j < HH; ++j)
            acc = fmaf(h_out[(size_t)b * HH + j], w_fc[o * 128 + j], acc);
        #pragma unroll 4
        for (int j = 0; j < HH; ++j)
            acc = fmaf(h_out[(size_t)(NB + b) * HH + j], w_fc[o * 128 + 64 + j], acc);
        out[b * 8 + o] = acc;
    }
}

extern "C" void kernel_launch(void* const* d_in, const int* in_sizes, int n_in,
                              void* d_out, int out_size, void* d_ws, size_t ws_size,
                              hipStream_t stream) {
    const float* x      = (const float*)d_in[0];
    const float* w_ih_f = (const float*)d_in[2];
    const float* w_hh_f = (const float*)d_in[3];
    const float* b_ih_f = (const float*)d_in[4];
    const float* b_hh_f = (const float*)d_in[5];
    const float* w_ih_b = (const float*)d_in[6];
    const float* w_hh_b = (const float*)d_in[7];
    const float* b_ih_b = (const float*)d_in[8];
    const float* b_hh_b = (const float*)d_in[9];
    const float* w_fc   = (const float*)d_in[10];
    const float* b_fc   = (const float*)d_in[11];
    float* out = (float*)d_out;

    const size_t pre_bytes = (size_t)2 * NB * TT * 256 * 2;   // 512 MiB bf16
    const size_t need      = pre_bytes + 64 * 1024;

    if (ws_size >= need) {
        unsigned short* pre = (unsigned short*)d_ws;
        float* h_out = (float*)((char*)d_ws + pre_bytes);
        lstm_proj_mfma<<<dim3(256), dim3(256), 0, stream>>>(
            x, w_ih_f, b_ih_f, b_hh_f, w_ih_b, b_ih_b, b_hh_b, pre);
        lstm_scan_quad<<<dim3(256), dim3(256), 0, stream>>>(
            pre, w_hh_f, w_hh_b, h_out);
        fc_kernel<<<dim3(128), dim3(64), 0, stream>>>(h_out, w_fc, b_fc, out);
    } else {
        float* h_out = (float*)d_ws;   // 64 KiB
        lstm_scan_fused_kernel<<<dim3(256), dim3(256), 0, stream>>>(
            x, w_ih_f, w_hh_f, b_ih_f, b_hh_f,
            w_ih_b, w_hh_b, b_ih_b, b_hh_b, h_out);
        fc_kernel<<<dim3(128), dim3(64), 0, stream>>>(h_out, w_fc, b_fc, out);
    }
}

// Round 8
// 2079.435 us; speedup vs baseline: 1.1764x; 1.1764x over previous
//
#include <hip/hip_runtime.h>
#include <hip/hip_bf16.h>

#define TT 4096
#define FF 80
#define HH 64
#define NB 128
#define TB 256    // proj: timesteps per block
#define CT 8      // proj: timesteps per staging phase
#define XPAD 104  // proj LDS row stride in bf16 elems

using short8  = __attribute__((ext_vector_type(8))) short;   // 8 bf16 = 4 VGPR
using floatx4 = __attribute__((ext_vector_type(4))) float;

__device__ __forceinline__ float sigm(float x)  { return __builtin_amdgcn_rcpf(1.0f + __expf(-x)); }
__device__ __forceinline__ float tanh_f(float x){ return 1.0f - 2.0f * __builtin_amdgcn_rcpf(1.0f + __expf(2.0f * x)); }

__device__ __forceinline__ unsigned short f2bf(float f) {    // RNE f32->bf16
    unsigned u = __builtin_bit_cast(unsigned, f);
    u += 0x7fffu + ((u >> 16) & 1u);
    return (unsigned short)(u >> 16);
}
__device__ __forceinline__ float bf2f(unsigned short u) {
    return __builtin_bit_cast(float, (unsigned)u << 16);
}
__device__ __forceinline__ unsigned packbf2(float a, float b) {
    return (unsigned)f2bf(a) | ((unsigned)f2bf(b) << 16);
}

// LDS-visibility-only barrier: global loads stay in flight across it.
__device__ __forceinline__ void bar_lgkm() {
    asm volatile("s_waitcnt lgkmcnt(0)" ::: "memory");
    __builtin_amdgcn_s_barrier();
}

__device__ __forceinline__ floatx4 mfma16(short8 a, short8 b, floatx4 c) {
    return __builtin_amdgcn_mfma_f32_16x16x32_bf16(a, b, c, 0, 0, 0);
}

// quad DPP shuffle (register-only): CTRL = quad_perm pattern
template <int CTRL>
__device__ __forceinline__ float qb(float v) {
    return __builtin_bit_cast(float,
        __builtin_amdgcn_mov_dpp(__builtin_bit_cast(int, v), CTRL, 0xF, 0xF, false));
}

// keep loaded weights as asm-defined SSA values (cannot be re-materialized
// by reloading from memory — the r1..r5 failure mode).
#define PIN4(vv) asm volatile("" : "+v"((vv).x), "+v"((vv).y), "+v"((vv).z), "+v"((vv).w))

// 16 scalar fmacs of one gate's j-slice: A += W(4xfloat4) . h(4xfloat4)
#define MACG(A, Wa, Wb, Wc, Wd)                                                              \
    A = fmaf((Wa).x,h0.x,A); A = fmaf((Wa).y,h0.y,A); A = fmaf((Wa).z,h0.z,A); A = fmaf((Wa).w,h0.w,A); \
    A = fmaf((Wb).x,h1.x,A); A = fmaf((Wb).y,h1.y,A); A = fmaf((Wb).z,h1.z,A); A = fmaf((Wb).w,h1.w,A); \
    A = fmaf((Wc).x,h2.x,A); A = fmaf((Wc).y,h2.y,A); A = fmaf((Wc).z,h2.z,A); A = fmaf((Wc).w,h2.w,A); \
    A = fmaf((Wd).x,h3.x,A); A = fmaf((Wd).y,h3.y,A); A = fmaf((Wd).z,h3.z,A); A = fmaf((Wd).w,h3.w,A);

// ---------------------------------------------------------------------------
// PROJ (MFMA) — unchanged from round 7 (passed).
// PRE[chain][t][perm(k)] with perm(k) = (k&63)*4 + (k>>6).
// ---------------------------------------------------------------------------
__global__ __launch_bounds__(256, 1)
void lstm_proj_mfma(const float* __restrict__ x,
                    const float* __restrict__ w_ih_f, const float* __restrict__ b_ih_f,
                    const float* __restrict__ b_hh_f,
                    const float* __restrict__ w_ih_b, const float* __restrict__ b_ih_b,
                    const float* __restrict__ b_hh_b,
                    unsigned short* __restrict__ pre)
{
    const int blk   = blockIdx.x;
    const int ttile = blk & 15;
    const int dgrp  = blk >> 4;
    const int dir   = dgrp >> 3;
    const int bgrp  = dgrp & 7;
    const int tid   = threadIdx.x;
    const int wv    = tid >> 6;
    const int l     = tid & 63;
    const int b16   = l & 15;
    const int g     = l >> 4;
    const int t0    = ttile * TB;

    const float* __restrict__ wih = dir ? w_ih_b : w_ih_f;
    const float* __restrict__ bi  = dir ? b_ih_b : b_ih_f;
    const float* __restrict__ bh  = dir ? b_hh_b : b_hh_f;

    short8 Bf[4][3];
    float  bias[4];
    #pragma unroll
    for (int tp = 0; tp < 4; ++tp) {
        const int n = 64 * wv + 16 * tp + b16;
        bias[tp] = bi[n] + bh[n];
        #pragma unroll
        for (int kap = 0; kap < 3; ++kap) {
            const int f0 = 32 * kap + 8 * g;
            float f[8];
            if (f0 < FF) {
                const float4 v0 = *reinterpret_cast<const float4*>(wih + n * FF + f0);
                const float4 v1 = *reinterpret_cast<const float4*>(wih + n * FF + f0 + 4);
                f[0]=v0.x; f[1]=v0.y; f[2]=v0.z; f[3]=v0.w;
                f[4]=v1.x; f[5]=v1.y; f[6]=v1.z; f[7]=v1.w;
            } else {
                #pragma unroll
                for (int j = 0; j < 8; ++j) f[j] = 0.0f;
            }
            short8 s;
            #pragma unroll
            for (int j = 0; j < 8; ++j) s[j] = (short)f2bf(f[j]);
            Bf[tp][kap] = s;
        }
    }

    __shared__ __align__(16) unsigned short xa[2][CT][16][XPAD];
    for (int i = tid; i < 2 * CT * 16 * XPAD / 2; i += 256)
        reinterpret_cast<unsigned*>(&xa[0][0][0][0])[i] = 0u;
    __syncthreads();

    const int nph = TB / CT;   // 32

    {   // prologue
        const int t0p = t0;
        const int te_base = dir ? (TT - CT - t0p) : t0p;
        float2 st[20];
        #pragma unroll
        for (int q = 0; q < 20; ++q) {
            const int i = q * 256 + tid;
            const int b = i / 320, r2 = i % 320;
            const int te_rel = r2 / 40, fq = r2 % 40;
            st[q] = *reinterpret_cast<const float2*>(
                x + ((size_t)(bgrp * 16 + b) * TT + te_base + te_rel) * FF + 2 * fq);
        }
        #pragma unroll
        for (int q = 0; q < 20; ++q) {
            const int i = q * 256 + tid;
            const int b = i / 320, r2 = i % 320;
            const int te_rel = r2 / 40, fq = r2 % 40;
            const int t_off = dir ? (CT - 1 - te_rel) : te_rel;
            *reinterpret_cast<unsigned*>(&xa[0][t_off][b][2 * fq]) = packbf2(st[q].x, st[q].y);
        }
    }
    __syncthreads();

    #pragma unroll 1
    for (int ph = 0; ph < nph; ++ph) {
        const int cur = ph & 1;
        const bool have = (ph + 1) < nph;

        float2 st[20];
        if (have) {
            const int t0p = t0 + (ph + 1) * CT;
            const int te_base = dir ? (TT - CT - t0p) : t0p;
            #pragma unroll
            for (int q = 0; q < 20; ++q) {
                const int i = q * 256 + tid;
                const int b = i / 320, r2 = i % 320;
                const int te_rel = r2 / 40, fq = r2 % 40;
                st[q] = *reinterpret_cast<const float2*>(
                    x + ((size_t)(bgrp * 16 + b) * TT + te_base + te_rel) * FF + 2 * fq);
            }
        }

        #pragma unroll
        for (int t_off = 0; t_off < CT; ++t_off) {
            short8 A[3];
            #pragma unroll
            for (int kap = 0; kap < 3; ++kap)
                A[kap] = *reinterpret_cast<const short8*>(&xa[cur][t_off][b16][32 * kap + 8 * g]);
            const int t = t0 + ph * CT + t_off;
            #pragma unroll
            for (int tp = 0; tp < 4; ++tp) {
                floatx4 acc = {bias[tp], bias[tp], bias[tp], bias[tp]};
                acc = mfma16(A[0], Bf[tp][0], acc);
                acc = mfma16(A[1], Bf[tp][1], acc);
                acc = mfma16(A[2], Bf[tp][2], acc);
                const int p = (16 * tp + b16) * 4 + wv;   // perm(n)
                #pragma unroll
                for (int r = 0; r < 4; ++r) {
                    const int bb = dir * NB + bgrp * 16 + 4 * g + r;
                    pre[((size_t)bb * TT + t) * 256 + p] = f2bf(acc[r]);
                }
            }
        }

        if (have) {
            #pragma unroll
            for (int q = 0; q < 20; ++q) {
                const int i = q * 256 + tid;
                const int b = i / 320, r2 = i % 320;
                const int te_rel = r2 / 40, fq = r2 % 40;
                const int t_off = dir ? (CT - 1 - te_rel) : te_rel;
                *reinterpret_cast<unsigned*>(&xa[cur ^ 1][t_off][b][2 * fq]) = packbf2(st[q].x, st[q].y);
            }
        }
        bar_lgkm();
    }
}

// ---------------------------------------------------------------------------
// SCAN v3 (quad j-split): 4 ds_read_b128/lane/step instead of 16; DPP quad
// butterfly for full gate sums; waves_per_eu(1,1) frees the VGPR budget.
// ---------------------------------------------------------------------------
__global__ void __launch_bounds__(256, 1) __attribute__((amdgpu_waves_per_eu(1, 1)))
lstm_scan_quad2(const unsigned short* __restrict__ pre,  // [256][TT][256] permuted
                const float* __restrict__ w_hh_f, const float* __restrict__ w_hh_b,
                float* __restrict__ h_out)               // [256][64]
{
    const int chain = blockIdx.x;
    const int dir   = chain >> 7;
    const int tid   = threadIdx.x;
    const int u     = tid >> 2;         // hidden unit 0..63
    const int q     = tid & 3;          // j-slice AND own-gate index

    const float* whh = (dir ? w_hh_b : w_hh_f);
    const float4* wr0 = reinterpret_cast<const float4*>(whh + (0 * 64 + u) * HH + 16 * q);
    const float4* wr1 = reinterpret_cast<const float4*>(whh + (1 * 64 + u) * HH + 16 * q);
    const float4* wr2 = reinterpret_cast<const float4*>(whh + (2 * 64 + u) * HH + 16 * q);
    const float4* wr3 = reinterpret_cast<const float4*>(whh + (3 * 64 + u) * HH + 16 * q);
    float4 w0 = wr0[0], w1 = wr0[1], w2 = wr0[2], w3 = wr0[3];   // gate i
    float4 w4 = wr1[0], w5 = wr1[1], w6 = wr1[2], w7 = wr1[3];   // gate f
    float4 w8 = wr2[0], w9 = wr2[1], wA = wr2[2], wB = wr2[3];   // gate g
    float4 wC = wr3[0], wD = wr3[1], wE = wr3[2], wF = wr3[3];   // gate o
    PIN4(w0); PIN4(w1); PIN4(w2); PIN4(w3);
    PIN4(w4); PIN4(w5); PIN4(w6); PIN4(w7);
    PIN4(w8); PIN4(w9); PIN4(wA); PIN4(wB);
    PIN4(wC); PIN4(wD); PIN4(wE); PIN4(wF);

    const float es = (q == 2) ?  2.0f : -1.0f;
    const float cA = (q == 2) ? -2.0f :  1.0f;
    const float cB = (q == 2) ?  1.0f :  0.0f;
    const bool  sb0 = (q & 1) != 0;
    const bool  sb1 = (q & 2) != 0;

    __shared__ __align__(16) float hbuf[2][HH];
    if (tid < 2 * HH) (&hbuf[0][0])[tid] = 0.0f;

    const unsigned short* __restrict__ prow =
        pre + (size_t)chain * TT * 256 + tid;
    unsigned short prr[4];
    #pragma unroll
    for (int d = 0; d < 4; ++d) prr[d] = prow[d * 256];

    float c = 0.0f, h = 0.0f;
    __syncthreads();

    #pragma unroll 1
    for (int t = 0; t < TT; t += 4) {
        #pragma unroll
        for (int d = 0; d < 4; ++d) {
            const int cur = d & 1;

            const float4* hb4 = reinterpret_cast<const float4*>(hbuf[cur]);
            const float4 h0 = hb4[4 * q + 0];
            const float4 h1 = hb4[4 * q + 1];
            const float4 h2 = hb4[4 * q + 2];
            const float4 h3 = hb4[4 * q + 3];

            float ai = 0.f, af = 0.f, ag = 0.f, ao = 0.f;
            MACG(ai, w0, w1, w2, w3);
            MACG(af, w4, w5, w6, w7);
            MACG(ag, w8, w9, wA, wB);
            MACG(ao, wC, wD, wE, wF);

            // capture old ring value, then issue reload for t+d+4
            const unsigned short pcur = prr[d];
            prr[d] = prow[(size_t)((t + d + 4) & (TT - 1)) * 256];

            // quad butterfly allreduce: [1,0,3,2]=0xB1, [2,3,0,1]=0x4E
            ai += qb<0xB1>(ai);  ai += qb<0x4E>(ai);
            af += qb<0xB1>(af);  af += qb<0x4E>(af);
            ag += qb<0xB1>(ag);  ag += qb<0x4E>(ag);
            ao += qb<0xB1>(ao);  ao += qb<0x4E>(ao);

            const float s01 = sb0 ? af : ai;
            const float s23 = sb0 ? ao : ag;
            const float gown = (sb1 ? s23 : s01) + bf2f(pcur);

            const float ex = __expf(es * gown);
            const float r  = __builtin_amdgcn_rcpf(1.0f + ex);
            const float a  = fmaf(cA, r, cB);

            const float gi = qb<0x00>(a);
            const float gf = qb<0x55>(a);
            const float gg = qb<0xAA>(a);
            const float go = qb<0xFF>(a);

            c = fmaf(gf, c, gi * gg);
            const float e2 = __expf(2.0f * c);
            const float r2 = __builtin_amdgcn_rcpf(1.0f + e2);
            h = go * fmaf(-2.0f, r2, 1.0f);

            if (q == 0) hbuf[cur ^ 1][u] = h;
            bar_lgkm();
        }
    }

    if (q == 0) h_out[(size_t)chain * HH + u] = h;
}

// ---------------------------------------------------------------------------
// Fallback: fully fused scan (round-1 kernel) if ws is too small for PRE.
// ---------------------------------------------------------------------------
__global__ __launch_bounds__(256, 1)
void lstm_scan_fused_kernel(const float* __restrict__ x,
                            const float* __restrict__ w_ih_f, const float* __restrict__ w_hh_f,
                            const float* __restrict__ b_ih_f, const float* __restrict__ b_hh_f,
                            const float* __restrict__ w_ih_b, const float* __restrict__ w_hh_b,
                            const float* __restrict__ b_ih_b, const float* __restrict__ b_hh_b,
                            float* __restrict__ h_out)
{
    const int blk = blockIdx.x;
    const int dir = blk >> 7;
    const int bat = blk & 127;
    const int tid = threadIdx.x;
    const int wv  = tid >> 6;
    const int ln  = tid & 63;

    const float* __restrict__ w_ih = dir ? w_ih_b : w_ih_f;
    const float* __restrict__ w_hh = dir ? w_hh_b : w_hh_f;
    const float* __restrict__ b_ih = dir ? b_ih_b : b_ih_f;
    const float* __restrict__ b_hh = dir ? b_hh_b : b_hh_f;

    float wi[FF], wh[HH];
    #pragma unroll
    for (int f = 0; f < FF; ++f) wi[f] = w_ih[tid * FF + f];
    #pragma unroll
    for (int j = 0; j < HH; ++j) wh[j] = w_hh[tid * HH + j];
    const float bias = b_ih[tid] + b_hh[tid];

    __shared__ float xs[2][FF];
    __shared__ float hbuf[4][HH];
    __shared__ float gbuf[2][256];

    const float* __restrict__ xrow = x + (size_t)bat * (TT * FF);
    float c = 0.0f, hreg = 0.0f;
    hbuf[wv][ln] = 0.0f;

    float xA = 0.0f;
    if (tid < FF) {
        xs[0][tid] = xrow[(size_t)(dir ? (TT - 1) : 0) * FF + tid];
        xA         = xrow[(size_t)(dir ? (TT - 2) : 1) * FF + tid];
    }
    __syncthreads();

    #pragma unroll 1
    for (int t = 0; t < TT; ++t) {
        const int cur = t & 1, nxt = cur ^ 1;
        float a0 = 0.f, a1 = 0.f, a2 = 0.f, a3 = 0.f;
        const float4* xs4 = reinterpret_cast<const float4*>(xs[cur]);
        #pragma unroll
        for (int f = 0; f < FF / 4; ++f) {
            float4 v = xs4[f];
            a0 = fmaf(wi[4*f+0], v.x, a0);
            a1 = fmaf(wi[4*f+1], v.y, a1);
            a2 = fmaf(wi[4*f+2], v.z, a2);
            a3 = fmaf(wi[4*f+3], v.w, a3);
        }
        const float4* hb4 = reinterpret_cast<const float4*>(hbuf[wv]);
        #pragma unroll
        for (int j = 0; j < HH / 4; ++j) {
            float4 v = hb4[j];
            a0 = fmaf(wh[4*j+0], v.x, a0);
            a1 = fmaf(wh[4*j+1], v.y, a1);
            a2 = fmaf(wh[4*j+2], v.z, a2);
            a3 = fmaf(wh[4*j+3], v.w, a3);
        }
        gbuf[cur][tid] = ((a0 + a1) + (a2 + a3)) + bias;

        if (tid < FF) {
            if (t + 1 < TT) xs[nxt][tid] = xA;
            if (t + 2 < TT) xA = xrow[(size_t)(dir ? (TT - 3 - t) : (t + 2)) * FF + tid];
        }
        __syncthreads();

        const float gi = gbuf[cur][ln];
        const float gf = gbuf[cur][64 + ln];
        const float gg = gbuf[cur][128 + ln];
        const float go = gbuf[cur][192 + ln];
        c    = sigm(gf) * c + sigm(gi) * tanh_f(gg);
        hreg = sigm(go) * tanh_f(c);
        hbuf[wv][ln] = hreg;
    }

    if (tid < HH) h_out[(size_t)(dir * 128 + bat) * HH + tid] = hreg;
}

__global__ __launch_bounds__(64, 1)
void fc_kernel(const float* __restrict__ h_out,   // [2][NB][HH]
               const float* __restrict__ w_fc,    // [8][128]
               const float* __restrict__ b_fc,    // [8]
               float* __restrict__ out)           // [NB][8]
{
    const int b = blockIdx.x;
    const int o = threadIdx.x;
    if (o < 8) {
        float acc = b_fc[o];
        #pragma unroll 4
        for (int j = 0; j < HH; ++j)
            acc = fmaf(h_out[(size_t)b * HH + j], w_fc[o * 128 + j], acc);
        #pragma unroll 4
        for (int j = 0; j < HH; ++j)
            acc = fmaf(h_out[(size_t)(NB + b) * HH + j], w_fc[o * 128 + 64 + j], acc);
        out[b * 8 + o] = acc;
    }
}

extern "C" void kernel_launch(void* const* d_in, const int* in_sizes, int n_in,
                              void* d_out, int out_size, void* d_ws, size_t ws_size,
                              hipStream_t stream) {
    const float* x      = (const float*)d_in[0];
    const float* w_ih_f = (const float*)d_in[2];
    const float* w_hh_f = (const float*)d_in[3];
    const float* b_ih_f = (const float*)d_in[4];
    const float* b_hh_f = (const float*)d_in[5];
    const float* w_ih_b = (const float*)d_in[6];
    const float* w_hh_b = (const float*)d_in[7];
    const float* b_ih_b = (const float*)d_in[8];
    const float* b_hh_b = (const float*)d_in[9];
    const float* w_fc   = (const float*)d_in[10];
    const float* b_fc   = (const float*)d_in[11];
    float* out = (float*)d_out;

    const size_t pre_bytes = (size_t)2 * NB * TT * 256 * 2;   // 512 MiB bf16
    const size_t need      = pre_bytes + 64 * 1024;

    if (ws_size >= need) {
        unsigned short* pre = (unsigned short*)d_ws;
        float* h_out = (float*)((char*)d_ws + pre_bytes);
        lstm_proj_mfma<<<dim3(256), dim3(256), 0, stream>>>(
            x, w_ih_f, b_ih_f, b_hh_f, w_ih_b, b_ih_b, b_hh_b, pre);
        lstm_scan_quad2<<<dim3(256), dim3(256), 0, stream>>>(
            pre, w_hh_f, w_hh_b, h_out);
        fc_kernel<<<dim3(128), dim3(64), 0, stream>>>(h_out, w_fc, b_fc, out);
    } else {
        float* h_out = (float*)d_ws;   // 64 KiB
        lstm_scan_fused_kernel<<<dim3(256), dim3(256), 0, stream>>>(
            x, w_ih_f, w_hh_f, b_ih_f, b_hh_f,
            w_ih_b, w_hh_b, b_ih_b, b_hh_b, h_out);
        fc_kernel<<<dim3(128), dim3(64), 0, stream>>>(h_out, w_fc, b_fc, out);
    }
}

// Round 9
// 1356.222 us; speedup vs baseline: 1.8037x; 1.5333x over previous
//
#include <hip/hip_runtime.h>
#include <hip/hip_bf16.h>

#define TT 4096
#define FF 80
#define HH 64
#define NB 128
#define TB 256    // proj: timesteps per block
#define CT 8      // proj: timesteps per staging phase
#define XPAD 104  // proj LDS row stride in bf16 elems

using short8  = __attribute__((ext_vector_type(8))) short;   // 8 bf16 = 4 VGPR
using floatx4 = __attribute__((ext_vector_type(4))) float;

__device__ __forceinline__ float sigm(float x)  { return __builtin_amdgcn_rcpf(1.0f + __expf(-x)); }
__device__ __forceinline__ float tanh_f(float x){ return 1.0f - 2.0f * __builtin_amdgcn_rcpf(1.0f + __expf(2.0f * x)); }

__device__ __forceinline__ unsigned short f2bf(float f) {    // RNE f32->bf16
    unsigned u = __builtin_bit_cast(unsigned, f);
    u += 0x7fffu + ((u >> 16) & 1u);
    return (unsigned short)(u >> 16);
}
__device__ __forceinline__ float bflo(unsigned u) { return __builtin_bit_cast(float, u << 16); }
__device__ __forceinline__ float bfhi(unsigned u) { return __builtin_bit_cast(float, u & 0xffff0000u); }
__device__ __forceinline__ unsigned packbf2(float a, float b) {
    return (unsigned)f2bf(a) | ((unsigned)f2bf(b) << 16);
}

// LDS-visibility-only barrier: global loads stay in flight across it.
__device__ __forceinline__ void bar_lgkm() {
    asm volatile("s_waitcnt lgkmcnt(0)" ::: "memory");
    __builtin_amdgcn_s_barrier();
}

__device__ __forceinline__ floatx4 mfma16(short8 a, short8 b, floatx4 c) {
    return __builtin_amdgcn_mfma_f32_16x16x32_bf16(a, b, c, 0, 0, 0);
}

// ---------------------------------------------------------------------------
// PROJ (MFMA) — unchanged from round 8 (passed, ~100-150 us).
// PRE[chain][t][unit*4 + gatetype] bf16.
// ---------------------------------------------------------------------------
__global__ __launch_bounds__(256, 1)
void lstm_proj_mfma(const float* __restrict__ x,
                    const float* __restrict__ w_ih_f, const float* __restrict__ b_ih_f,
                    const float* __restrict__ b_hh_f,
                    const float* __restrict__ w_ih_b, const float* __restrict__ b_ih_b,
                    const float* __restrict__ b_hh_b,
                    unsigned short* __restrict__ pre)
{
    const int blk   = blockIdx.x;
    const int ttile = blk & 15;
    const int dgrp  = blk >> 4;
    const int dir   = dgrp >> 3;
    const int bgrp  = dgrp & 7;
    const int tid   = threadIdx.x;
    const int wv    = tid >> 6;
    const int l     = tid & 63;
    const int b16   = l & 15;
    const int g     = l >> 4;
    const int t0    = ttile * TB;

    const float* __restrict__ wih = dir ? w_ih_b : w_ih_f;
    const float* __restrict__ bi  = dir ? b_ih_b : b_ih_f;
    const float* __restrict__ bh  = dir ? b_hh_b : b_hh_f;

    short8 Bf[4][3];
    float  bias[4];
    #pragma unroll
    for (int tp = 0; tp < 4; ++tp) {
        const int n = 64 * wv + 16 * tp + b16;
        bias[tp] = bi[n] + bh[n];
        #pragma unroll
        for (int kap = 0; kap < 3; ++kap) {
            const int f0 = 32 * kap + 8 * g;
            float f[8];
            if (f0 < FF) {
                const float4 v0 = *reinterpret_cast<const float4*>(wih + n * FF + f0);
                const float4 v1 = *reinterpret_cast<const float4*>(wih + n * FF + f0 + 4);
                f[0]=v0.x; f[1]=v0.y; f[2]=v0.z; f[3]=v0.w;
                f[4]=v1.x; f[5]=v1.y; f[6]=v1.z; f[7]=v1.w;
            } else {
                #pragma unroll
                for (int j = 0; j < 8; ++j) f[j] = 0.0f;
            }
            short8 s;
            #pragma unroll
            for (int j = 0; j < 8; ++j) s[j] = (short)f2bf(f[j]);
            Bf[tp][kap] = s;
        }
    }

    __shared__ __align__(16) unsigned short xa[2][CT][16][XPAD];
    for (int i = tid; i < 2 * CT * 16 * XPAD / 2; i += 256)
        reinterpret_cast<unsigned*>(&xa[0][0][0][0])[i] = 0u;
    __syncthreads();

    const int nph = TB / CT;   // 32

    {   // prologue
        const int t0p = t0;
        const int te_base = dir ? (TT - CT - t0p) : t0p;
        float2 st[20];
        #pragma unroll
        for (int q = 0; q < 20; ++q) {
            const int i = q * 256 + tid;
            const int b = i / 320, r2 = i % 320;
            const int te_rel = r2 / 40, fq = r2 % 40;
            st[q] = *reinterpret_cast<const float2*>(
                x + ((size_t)(bgrp * 16 + b) * TT + te_base + te_rel) * FF + 2 * fq);
        }
        #pragma unroll
        for (int q = 0; q < 20; ++q) {
            const int i = q * 256 + tid;
            const int b = i / 320, r2 = i % 320;
            const int te_rel = r2 / 40, fq = r2 % 40;
            const int t_off = dir ? (CT - 1 - te_rel) : te_rel;
            *reinterpret_cast<unsigned*>(&xa[0][t_off][b][2 * fq]) = packbf2(st[q].x, st[q].y);
        }
    }
    __syncthreads();

    #pragma unroll 1
    for (int ph = 0; ph < nph; ++ph) {
        const int cur = ph & 1;
        const bool have = (ph + 1) < nph;

        float2 st[20];
        if (have) {
            const int t0p = t0 + (ph + 1) * CT;
            const int te_base = dir ? (TT - CT - t0p) : t0p;
            #pragma unroll
            for (int q = 0; q < 20; ++q) {
                const int i = q * 256 + tid;
                const int b = i / 320, r2 = i % 320;
                const int te_rel = r2 / 40, fq = r2 % 40;
                st[q] = *reinterpret_cast<const float2*>(
                    x + ((size_t)(bgrp * 16 + b) * TT + te_base + te_rel) * FF + 2 * fq);
            }
        }

        #pragma unroll
        for (int t_off = 0; t_off < CT; ++t_off) {
            short8 A[3];
            #pragma unroll
            for (int kap = 0; kap < 3; ++kap)
                A[kap] = *reinterpret_cast<const short8*>(&xa[cur][t_off][b16][32 * kap + 8 * g]);
            const int t = t0 + ph * CT + t_off;
            #pragma unroll
            for (int tp = 0; tp < 4; ++tp) {
                floatx4 acc = {bias[tp], bias[tp], bias[tp], bias[tp]};
                acc = mfma16(A[0], Bf[tp][0], acc);
                acc = mfma16(A[1], Bf[tp][1], acc);
                acc = mfma16(A[2], Bf[tp][2], acc);
                const int p = (16 * tp + b16) * 4 + wv;   // unit*4 + gatetype
                #pragma unroll
                for (int r = 0; r < 4; ++r) {
                    const int bb = dir * NB + bgrp * 16 + 4 * g + r;
                    pre[((size_t)bb * TT + t) * 256 + p] = f2bf(acc[r]);
                }
            }
        }

        if (have) {
            #pragma unroll
            for (int q = 0; q < 20; ++q) {
                const int i = q * 256 + tid;
                const int b = i / 320, r2 = i % 320;
                const int te_rel = r2 / 40, fq = r2 % 40;
                const int t_off = dir ? (CT - 1 - te_rel) : te_rel;
                *reinterpret_cast<unsigned*>(&xa[cur ^ 1][t_off][b][2 * fq]) = packbf2(st[q].x, st[q].y);
            }
        }
        bar_lgkm();
    }
}

// ---------------------------------------------------------------------------
// SCAN v4 (MFMA matvec, 256 blocks = 1 chain/CU, 4 waves):
// Per step, G[1x256] = h[1x64] @ W_hh^T via 8 MFMAs/wave. A = h as row 0 of a
// 16x16x32 tile (rows 1-15 read a zeroed LDS region, branchless). B-fragments
// (bf16, 32 regs) are MFMA operands -> live happily in (A)VGPRs, consumed in
// place: no allocator fight, no per-use copies. C layout (m89) drops all 4
// gate sums of unit u = 16*wv + lane into lanes 0-15 reg0 -> lane-local cell
// update; h -> bf16 -> 1 ds_write_b16; one lgkm-only barrier/step; PRE ring
// (distance 4, 8B/lane) rides across the barrier.
// ---------------------------------------------------------------------------
__global__ __launch_bounds__(256, 1)
void lstm_scan_mfma1(const unsigned short* __restrict__ pre,  // [256][TT][256]
                     const float* __restrict__ w_hh_f, const float* __restrict__ w_hh_b,
                     float* __restrict__ h_out)               // [256][64]
{
    const int chain = blockIdx.x;       // dir*128 + bat
    const int dir   = chain >> 7;
    const int tid   = threadIdx.x;
    const int wv    = tid >> 6;         // unit window: 16*wv .. 16*wv+15
    const int l     = tid & 63;
    const int b16   = l & 15;           // A row / C col
    const int g4    = l >> 4;           // k-group
    const bool actC = (g4 == 0);        // C row 0 lanes: cell owners (l = 0..15)
    const int  u    = 16 * wv + b16;    // this lane's unit (valid when actC)

    const float* __restrict__ whh = dir ? w_hh_b : w_hh_f;

    // B-fragments: gate gt (0:i 1:f 2:g 3:o), kap (K chunk).
    // col n = gt*64 + 16*wv + b16 ; k = 32*kap + 8*g4 + j
    short8 Bf[4][2];
    #pragma unroll
    for (int gt = 0; gt < 4; ++gt) {
        const int n = gt * 64 + 16 * wv + b16;
        #pragma unroll
        for (int kap = 0; kap < 2; ++kap) {
            const float4 v0 = *reinterpret_cast<const float4*>(whh + n * HH + 32 * kap + 8 * g4);
            const float4 v1 = *reinterpret_cast<const float4*>(whh + n * HH + 32 * kap + 8 * g4 + 4);
            short8 s;
            s[0]=(short)f2bf(v0.x); s[1]=(short)f2bf(v0.y); s[2]=(short)f2bf(v0.z); s[3]=(short)f2bf(v0.w);
            s[4]=(short)f2bf(v1.x); s[5]=(short)f2bf(v1.y); s[6]=(short)f2bf(v1.z); s[7]=(short)f2bf(v1.w);
            Bf[gt][kap] = s;
        }
    }

    // LDS: bytes [0,128) = h buf0 (bf16[64]), [128,256) = h buf1,
    //      [256,384) = permanently-zero region (A rows 1-15 read here).
    __shared__ __align__(16) unsigned short hls[192];
    if (tid < 96) reinterpret_cast<unsigned*>(hls)[tid] = 0u;

    // PRE ring: lane (actC) reads uint2 = {i,f | g,o} bf16 at [chain][t][u*4].
    const uint2* __restrict__ prow = reinterpret_cast<const uint2*>(
        pre + (size_t)chain * TT * 256 + u * 4);
    uint2 prr[4];
    if (actC) {
        #pragma unroll
        for (int d = 0; d < 4; ++d) prr[d] = prow[(size_t)d * 64];   // t stride = 64 uint2
    }

    float c = 0.0f, h = 0.0f;
    __syncthreads();

    const char* lb = reinterpret_cast<const char*>(hls);
    char* lw = reinterpret_cast<char*>(hls);

    #pragma unroll 1
    for (int t = 0; t < TT; t += 4) {
        #pragma unroll
        for (int d = 0; d < 4; ++d) {
            const int cur = d & 1;       // (t+d)&1 since t%4==0

            // A fragments: row-0 lanes read h(t) bf16; others read zeros.
            const int abase = (b16 == 0 ? 128 * cur : 256) + 16 * g4;
            const short8 A0 = *reinterpret_cast<const short8*>(lb + abase);
            const short8 A1 = *reinterpret_cast<const short8*>(lb + abase + 64);

            // capture PRE for this step, then reload ring slot for t+d+4
            uint2 pc = prr[d];
            if (actC) prr[d] = prow[(size_t)((t + d + 4) & (TT - 1)) * 64];

            const floatx4 z = {0.f, 0.f, 0.f, 0.f};
            floatx4 ci = mfma16(A1, Bf[0][1], mfma16(A0, Bf[0][0], z));
            floatx4 cf = mfma16(A1, Bf[1][1], mfma16(A0, Bf[1][0], z));
            floatx4 cg = mfma16(A1, Bf[2][1], mfma16(A0, Bf[2][0], z));
            floatx4 co = mfma16(A1, Bf[3][1], mfma16(A0, Bf[3][0], z));

            if (actC) {
                const float gi = bflo(pc.x) + ci[0];
                const float gf = bfhi(pc.x) + cf[0];
                const float gg = bflo(pc.y) + cg[0];
                const float go = bfhi(pc.y) + co[0];
                c = fmaf(sigm(gf), c, sigm(gi) * tanh_f(gg));
                h = sigm(go) * tanh_f(c);
                *reinterpret_cast<unsigned short*>(lw + 128 * (cur ^ 1) + 2 * u) = f2bf(h);
            }
            bar_lgkm();                  // LDS visibility only; ring stays in flight
        }
    }

    if (actC) h_out[(size_t)chain * HH + u] = h;
}

// ---------------------------------------------------------------------------
// Fallback: fully fused scan (round-1 kernel) if ws is too small for PRE.
// ---------------------------------------------------------------------------
__global__ __launch_bounds__(256, 1)
void lstm_scan_fused_kernel(const float* __restrict__ x,
                            const float* __restrict__ w_ih_f, const float* __restrict__ w_hh_f,
                            const float* __restrict__ b_ih_f, const float* __restrict__ b_hh_f,
                            const float* __restrict__ w_ih_b, const float* __restrict__ w_hh_b,
                            const float* __restrict__ b_ih_b, const float* __restrict__ b_hh_b,
                            float* __restrict__ h_out)
{
    const int blk = blockIdx.x;
    const int dir = blk >> 7;
    const int bat = blk & 127;
    const int tid = threadIdx.x;
    const int wv  = tid >> 6;
    const int ln  = tid & 63;

    const float* __restrict__ w_ih = dir ? w_ih_b : w_ih_f;
    const float* __restrict__ w_hh = dir ? w_hh_b : w_hh_f;
    const float* __restrict__ b_ih = dir ? b_ih_b : b_ih_f;
    const float* __restrict__ b_hh = dir ? b_hh_b : b_hh_f;

    float wi[FF], wh[HH];
    #pragma unroll
    for (int f = 0; f < FF; ++f) wi[f] = w_ih[tid * FF + f];
    #pragma unroll
    for (int j = 0; j < HH; ++j) wh[j] = w_hh[tid * HH + j];
    const float bias = b_ih[tid] + b_hh[tid];

    __shared__ float xs[2][FF];
    __shared__ float hbuf[4][HH];
    __shared__ float gbuf[2][256];

    const float* __restrict__ xrow = x + (size_t)bat * (TT * FF);
    float c = 0.0f, hreg = 0.0f;
    hbuf[wv][ln] = 0.0f;

    float xA = 0.0f;
    if (tid < FF) {
        xs[0][tid] = xrow[(size_t)(dir ? (TT - 1) : 0) * FF + tid];
        xA         = xrow[(size_t)(dir ? (TT - 2) : 1) * FF + tid];
    }
    __syncthreads();

    #pragma unroll 1
    for (int t = 0; t < TT; ++t) {
        const int cur = t & 1, nxt = cur ^ 1;
        float a0 = 0.f, a1 = 0.f, a2 = 0.f, a3 = 0.f;
        const float4* xs4 = reinterpret_cast<const float4*>(xs[cur]);
        #pragma unroll
        for (int f = 0; f < FF / 4; ++f) {
            float4 v = xs4[f];
            a0 = fmaf(wi[4*f+0], v.x, a0);
            a1 = fmaf(wi[4*f+1], v.y, a1);
            a2 = fmaf(wi[4*f+2], v.z, a2);
            a3 = fmaf(wi[4*f+3], v.w, a3);
        }
        const float4* hb4 = reinterpret_cast<const float4*>(hbuf[wv]);
        #pragma unroll
        for (int j = 0; j < HH / 4; ++j) {
            float4 v = hb4[j];
            a0 = fmaf(wh[4*j+0], v.x, a0);
            a1 = fmaf(wh[4*j+1], v.y, a1);
            a2 = fmaf(wh[4*j+2], v.z, a2);
            a3 = fmaf(wh[4*j+3], v.w, a3);
        }
        gbuf[cur][tid] = ((a0 + a1) + (a2 + a3)) + bias;

        if (tid < FF) {
            if (t + 1 < TT) xs[nxt][tid] = xA;
            if (t + 2 < TT) xA = xrow[(size_t)(dir ? (TT - 3 - t) : (t + 2)) * FF + tid];
        }
        __syncthreads();

        const float gi = gbuf[cur][ln];
        const float gf = gbuf[cur][64 + ln];
        const float gg = gbuf[cur][128 + ln];
        const float go = gbuf[cur][192 + ln];
        c    = sigm(gf) * c + sigm(gi) * tanh_f(gg);
        hreg = sigm(go) * tanh_f(c);
        hbuf[wv][ln] = hreg;
    }

    if (tid < HH) h_out[(size_t)(dir * 128 + bat) * HH + tid] = hreg;
}

__global__ __launch_bounds__(64, 1)
void fc_kernel(const float* __restrict__ h_out,   // [2][NB][HH]
               const float* __restrict__ w_fc,    // [8][128]
               const float* __restrict__ b_fc,    // [8]
               float* __restrict__ out)           // [NB][8]
{
    const int b = blockIdx.x;
    const int o = threadIdx.x;
    if (o < 8) {
        float acc = b_fc[o];
        #pragma unroll 4
        for (int j = 0; j < HH; ++j)
            acc = fmaf(h_out[(size_t)b * HH + j], w_fc[o * 128 + j], acc);
        #pragma unroll 4
        for (int j = 0; j < HH; ++j)
            acc = fmaf(h_out[(size_t)(NB + b) * HH + j], w_fc[o * 128 + 64 + j], acc);
        out[b * 8 + o] = acc;
    }
}

extern "C" void kernel_launch(void* const* d_in, const int* in_sizes, int n_in,
                              void* d_out, int out_size, void* d_ws, size_t ws_size,
                              hipStream_t stream) {
    const float* x      = (const float*)d_in[0];
    const float* w_ih_f = (const float*)d_in[2];
    const float* w_hh_f = (const float*)d_in[3];
    const float* b_ih_f = (const float*)d_in[4];
    const float* b_hh_f = (const float*)d_in[5];
    const float* w_ih_b = (const float*)d_in[6];
    const float* w_hh_b = (const float*)d_in[7];
    const float* b_ih_b = (const float*)d_in[8];
    const float* b_hh_b = (const float*)d_in[9];
    const float* w_fc   = (const float*)d_in[10];
    const float* b_fc   = (const float*)d_in[11];
    float* out = (float*)d_out;

    const size_t pre_bytes = (size_t)2 * NB * TT * 256 * 2;   // 512 MiB bf16
    const size_t need      = pre_bytes + 64 * 1024;

    if (ws_size >= need) {
        unsigned short* pre = (unsigned short*)d_ws;
        float* h_out = (float*)((char*)d_ws + pre_bytes);
        lstm_proj_mfma<<<dim3(256), dim3(256), 0, stream>>>(
            x, w_ih_f, b_ih_f, b_hh_f, w_ih_b, b_ih_b, b_hh_b, pre);
        lstm_scan_mfma1<<<dim3(256), dim3(256), 0, stream>>>(
            pre, w_hh_f, w_hh_b, h_out);
        fc_kernel<<<dim3(128), dim3(64), 0, stream>>>(h_out, w_fc, b_fc, out);
    } else {
        float* h_out = (float*)d_ws;   // 64 KiB
        lstm_scan_fused_kernel<<<dim3(256), dim3(256), 0, stream>>>(
            x, w_ih_f, w_hh_f, b_ih_f, b_hh_f,
            w_ih_b, w_hh_b, b_ih_b, b_hh_b, h_out);
        fc_kernel<<<dim3(128), dim3(64), 0, stream>>>(h_out, w_fc, b_fc, out);
    }
}